// Round 2
// baseline (430.501 us; speedup 1.0000x reference)
//
#include <hip/hip_runtime.h>
#include <stdint.h>

#define AS1 __attribute__((address_space(1)))
#define AS3 __attribute__((address_space(3)))

typedef __attribute__((ext_vector_type(4))) int i32x4;
typedef __attribute__((ext_vector_type(16))) int i32x16;

// ---------------- blend: blended[g] = sum_p routing[p] * ps[p*G+g] ----------
__global__ void blend_k(const float* __restrict__ ps, const float* __restrict__ rt,
                        float* __restrict__ blended, int G, int P) {
  int g = blockIdx.x * blockDim.x + threadIdx.x;
  if (g >= G) return;
  float s = 0.f;
  for (int p = 0; p < P; ++p) s += rt[p] * ps[(size_t)p * G + g];
  blended[g] = s;
}

__device__ __forceinline__ int q8(float v, float s) {
  int q = (int)rintf(v * s);
  q = q > 127 ? 127 : q;
  q = q < -127 ? -127 : q;
  return q & 0xff;
}

// ---------------- quantize W: w_q[i] = sign(signs[i]) * round(127*blended[i/128])
__global__ void quant_w_k(const float4* __restrict__ signs, const float* __restrict__ blended,
                          int4* __restrict__ wq, int n16) {
  int t = blockIdx.x * blockDim.x + threadIdx.x;
  if (t >= n16) return;
  float bl = blended[t >> 3];             // (t*16) >> 7
  int q = (int)rintf(bl * 127.f);
  q = q > 127 ? 127 : q; q = q < 1 ? 1 : q;
  int b[16];
#pragma unroll
  for (int i = 0; i < 4; ++i) {
    float4 s = signs[t * 4 + i];
    b[i * 4 + 0] = (s.x >= 0.f ? q : -q) & 0xff;
    b[i * 4 + 1] = (s.y >= 0.f ? q : -q) & 0xff;
    b[i * 4 + 2] = (s.z >= 0.f ? q : -q) & 0xff;
    b[i * 4 + 3] = (s.w >= 0.f ? q : -q) & 0xff;
  }
  int4 o;
  o.x = b[0] | (b[1] << 8) | (b[2] << 16) | (b[3] << 24);
  o.y = b[4] | (b[5] << 8) | (b[6] << 16) | (b[7] << 24);
  o.z = b[8] | (b[9] << 8) | (b[10] << 16) | (b[11] << 24);
  o.w = b[12] | (b[13] << 8) | (b[14] << 16) | (b[15] << 24);
  wq[t] = o;
}

// ---------------- quantize X per row: one block per row (K=4096, 256 thr) ----
__global__ __launch_bounds__(256) void quant_x_k(const float4* __restrict__ x,
                                                 int* __restrict__ xq,
                                                 float* __restrict__ rowinv, int K) {
  const int m = blockIdx.x;
  const int t = threadIdx.x;
  const int lane = t & 63;
  const int wave = t >> 6;
  const float4* xr = x + (size_t)m * (K / 4);
  float4 v[4];
  float amax = 0.f;
#pragma unroll
  for (int i = 0; i < 4; ++i) {
    v[i] = xr[t + 256 * i];
    amax = fmaxf(amax, fmaxf(fmaxf(fabsf(v[i].x), fabsf(v[i].y)),
                             fmaxf(fabsf(v[i].z), fabsf(v[i].w))));
  }
#pragma unroll
  for (int off = 1; off < 64; off <<= 1)
    amax = fmaxf(amax, __shfl_xor(amax, off));
  __shared__ float red[4];
  if (lane == 0) red[wave] = amax;
  __syncthreads();
  amax = fmaxf(fmaxf(red[0], red[1]), fmaxf(red[2], red[3]));
  const float s = 127.f / amax;
  if (t == 0) rowinv[m] = amax / (127.f * 127.f);
  int* xo = xq + (size_t)m * (K / 4);
#pragma unroll
  for (int i = 0; i < 4; ++i) {
    int p = q8(v[i].x, s) | (q8(v[i].y, s) << 8) | (q8(v[i].z, s) << 16) | (q8(v[i].w, s) << 24);
    xo[t + 256 * i] = p;
  }
}

// ---------------- i8 GEMM: C[M,N] = (A[M,K] * B[N,K]^T) * rowinv[m] ---------
// 256x256 tile, 8 waves (2Mx4N), per-wave 128x64 via 4x2 of mfma_i32_32x32x32_i8.
// K is consumed in 64-byte half-tiles through a 4-deep LDS ring (4 x 32KiB =
// 128KiB): while computing half h, halves h+1..h+3 are staging in flight.
// Counted s_waitcnt vmcnt(8) at each boundary (never 0 until the tail) + raw
// s_barrier (no implicit drain) -> loads get ~3 iterations of hiding.
// LDS swizzle: 64B rows of 4x16B slots; slot = chunk ^ ((row>>1)&3). Applied on
// BOTH sides: pre-swizzled global source addrs feed linear global_load_lds
// dests; ds_read applies the same XOR (rule 21: both-sides-or-neither).
// vmcnt accounting is exact: the loop body contains exactly 4 VMEM ops/wave
// (the staging loads) and no other global/flat ops.
#define BM 256
#define BN 256

__global__ __launch_bounds__(512, 2) void gemm_i8_k(
    const signed char* __restrict__ A, const signed char* __restrict__ B,
    const float* __restrict__ rowinv, float* __restrict__ C, int M, int N, int K) {
  __shared__ __align__(16) signed char lds[4][2][256 * 64];   // [buf][A/B][row*64+slot*16]
  const int tid  = threadIdx.x;
  const int lane = tid & 63;
  const int wave = tid >> 6;

  // bijective XCD swizzle (nwg = 512, divisible by 8)
  int bid = blockIdx.y * gridDim.x + blockIdx.x;
  const int nwg = gridDim.x * gridDim.y;
  const int cpx = nwg >> 3;
  bid = (bid & 7) * cpx + (bid >> 3);
  const int nbx = N / BN;
  const int bn = (bid % nbx) * BN;
  const int bm = (bid / nbx) * BM;

  const int wm = (wave >> 2) * 128;
  const int wn = (wave & 3) * 64;
  const int fl = lane & 31;
  const int fh = lane >> 5;
  const int sx = (fl >> 1) & 3;   // read-side swizzle: slot = chunk ^ sx

  i32x16 acc[4][2];
#pragma unroll
  for (int i = 0; i < 4; ++i)
#pragma unroll
    for (int j = 0; j < 2; ++j)
#pragma unroll
      for (int r = 0; r < 16; ++r) acc[i][j][r] = 0;

  // Staging geometry: one global_load_lds covers 64 lanes x 16B = 16 rows of
  // 64B. Per wave per half: 2 A-instrs + 2 B-instrs (32 rows each); 8 waves
  // cover all 256 rows. LDS dest is linear (base + lane*16): lane l lands at
  // row R0+(l>>2), slot l&3. Source chunk pre-swizzled so that slot s holds
  // chunk s ^ ((row>>1)&3):  c = (l&3) ^ ((l>>3)&3)  (since R0 % 16 == 0).
  const int sl   = (lane & 3) ^ ((lane >> 3) & 3);
  const int srow = lane >> 2;
  const int rA0 = 16 * (2 * wave + 0) + srow;
  const int rA1 = 16 * (2 * wave + 1) + srow;
  const signed char* gA0 = A + (size_t)(bm + rA0) * K + sl * 16;
  const signed char* gA1 = A + (size_t)(bm + rA1) * K + sl * 16;
  const signed char* gB0 = B + (size_t)(bn + rA0) * K + sl * 16;
  const signed char* gB1 = B + (size_t)(bn + rA1) * K + sl * 16;

#define STAGE(hh)                                                                \
  {                                                                              \
    const int q_  = (hh) & 3;                                                    \
    const int ko_ = (hh) * 64;                                                   \
    __builtin_amdgcn_global_load_lds((AS1 unsigned int*)(gA0 + ko_),             \
        (AS3 unsigned int*)(&lds[q_][0][(2 * wave + 0) * 1024]), 16, 0, 0);      \
    __builtin_amdgcn_global_load_lds((AS1 unsigned int*)(gA1 + ko_),             \
        (AS3 unsigned int*)(&lds[q_][0][(2 * wave + 1) * 1024]), 16, 0, 0);      \
    __builtin_amdgcn_global_load_lds((AS1 unsigned int*)(gB0 + ko_),             \
        (AS3 unsigned int*)(&lds[q_][1][(2 * wave + 0) * 1024]), 16, 0, 0);      \
    __builtin_amdgcn_global_load_lds((AS1 unsigned int*)(gB1 + ko_),             \
        (AS3 unsigned int*)(&lds[q_][1][(2 * wave + 1) * 1024]), 16, 0, 0);      \
  }

  const int NH = K >> 6;   // 64-byte halves of K
  STAGE(0); STAGE(1); STAGE(2);
  asm volatile("s_waitcnt vmcnt(8)" ::: "memory");   // half 0 resident
  __builtin_amdgcn_s_barrier();

  for (int h = 0; h < NH; ++h) {
    if (h + 3 < NH) STAGE(h + 3);   // overwrites buf (h-1)&3: safe post-barrier

    const signed char* Ab = &lds[h & 3][0][0];
    const signed char* Bb = &lds[h & 3][1][0];
    i32x4 af[2][4], bf[2][2];
#pragma unroll
    for (int ks = 0; ks < 2; ++ks) {
      const int c = ks * 2 + fh;               // 16B chunk within the 64B half
#pragma unroll
      for (int mi = 0; mi < 4; ++mi) {
        const int r = wm + mi * 32 + fl;
        af[ks][mi] = *(const i32x4*)(Ab + r * 64 + ((c ^ sx) * 16));
      }
#pragma unroll
      for (int ni = 0; ni < 2; ++ni) {
        const int r = wn + ni * 32 + fl;
        bf[ks][ni] = *(const i32x4*)(Bb + r * 64 + ((c ^ sx) * 16));
      }
    }

    __builtin_amdgcn_s_setprio(1);
#pragma unroll
    for (int ks = 0; ks < 2; ++ks)
#pragma unroll
      for (int mi = 0; mi < 4; ++mi)
#pragma unroll
        for (int ni = 0; ni < 2; ++ni)
          acc[mi][ni] = __builtin_amdgcn_mfma_i32_32x32x32_i8(
              af[ks][mi], bf[ks][ni], acc[mi][ni], 0, 0, 0);
    __builtin_amdgcn_s_setprio(0);

    // retire through half h+1 (needed next iter); keep the rest in flight
    if (h + 3 < NH)      asm volatile("s_waitcnt vmcnt(8)" ::: "memory");
    else if (h + 2 < NH) asm volatile("s_waitcnt vmcnt(4)" ::: "memory");
    else if (h + 1 < NH) asm volatile("s_waitcnt vmcnt(0)" ::: "memory");
    __builtin_amdgcn_s_barrier();
  }
#undef STAGE

  // C/D layout (32x32): col = lane&31, row = (reg&3) + 8*(reg>>2) + 4*(lane>>5)
#pragma unroll
  for (int mi = 0; mi < 4; ++mi) {
    const int rbase = bm + wm + mi * 32 + 4 * fh;
    float ri[16];
#pragma unroll
    for (int r = 0; r < 16; ++r) ri[r] = rowinv[rbase + (r & 3) + 8 * (r >> 2)];
#pragma unroll
    for (int ni = 0; ni < 2; ++ni) {
      const int col = bn + wn + ni * 32 + fl;
#pragma unroll
      for (int r = 0; r < 16; ++r) {
        const int row = rbase + (r & 3) + 8 * (r >> 2);
        C[(size_t)row * N + col] = (float)acc[mi][ni][r] * ri[r];
      }
    }
  }
}

// Safety-net exact fp32 kernel (only if ws_size too small) — slow but correct.
__global__ void naive_k(const float* __restrict__ x, const float* __restrict__ signs,
                        const float* __restrict__ ps, const float* __restrict__ rt,
                        float* __restrict__ out, int M, int N, int K, int P) {
  int idx = blockIdx.x * blockDim.x + threadIdx.x;
  if (idx >= M * N) return;
  int m = idx / N, n = idx % N;
  const float* xr = x + (size_t)m * K;
  const float* wr = signs + (size_t)n * K;
  const int NG = K / 128;
  const size_t G = (size_t)N * NG;
  float acc = 0.f;
  for (int g = 0; g < NG; ++g) {
    float sc = 0.f;
    int gi = n * NG + g;
    for (int p = 0; p < P; ++p) sc += rt[p] * ps[(size_t)p * G + gi];
    float s2 = 0.f;
    for (int kk = 0; kk < 128; ++kk) s2 += xr[g * 128 + kk] * wr[g * 128 + kk];
    acc += sc * s2;
  }
  out[idx] = acc;
}

extern "C" void kernel_launch(void* const* d_in, const int* in_sizes, int n_in,
                              void* d_out, int out_size, void* d_ws, size_t ws_size,
                              hipStream_t stream) {
  const float* x     = (const float*)d_in[0];
  const float* signs = (const float*)d_in[1];
  const float* ps    = (const float*)d_in[2];
  const float* rt    = (const float*)d_in[3];
  float* out = (float*)d_out;

  const int K = 4096, N = 4096, GS = 128;
  const int M = in_sizes[0] / K;   // 8192
  const int G = N / GS * K;        // 131072 flat groups over [N*K]
  const int P = in_sizes[3];       // 8

  const size_t xq_bytes = (size_t)M * K;       // 33.5 MB
  const size_t wq_bytes = (size_t)N * K;       // 16.8 MB
  const size_t bl_bytes = (size_t)G * 4;       // 0.5 MB
  const size_t ri_bytes = (size_t)M * 4;       // 32 KB
  const size_t need = xq_bytes + wq_bytes + bl_bytes + ri_bytes;

  if (ws_size >= need && (M % BM) == 0) {
    signed char* xq = (signed char*)d_ws;
    signed char* wq = (signed char*)((char*)d_ws + xq_bytes);
    float* blended  = (float*)((char*)d_ws + xq_bytes + wq_bytes);
    float* rowinv   = (float*)((char*)d_ws + xq_bytes + wq_bytes + bl_bytes);

    blend_k<<<(G + 255) / 256, 256, 0, stream>>>(ps, rt, blended, G, P);

    const int n16w = N * K / 16;
    quant_w_k<<<(n16w + 255) / 256, 256, 0, stream>>>(
        (const float4*)signs, blended, (int4*)wq, n16w);

    quant_x_k<<<M, 256, 0, stream>>>((const float4*)x, (int*)xq, rowinv, K);

    dim3 grid(N / BN, M / BM);
    gemm_i8_k<<<grid, 512, 0, stream>>>(xq, wq, rowinv, out, M, N, K);
  } else {
    const size_t total = (size_t)M * N;
    naive_k<<<(int)((total + 255) / 256), 256, 0, stream>>>(
        x, signs, ps, rt, out, M, N, K, P);
  }
}

// Round 3
// 424.854 us; speedup vs baseline: 1.0133x; 1.0133x over previous
//
#include <hip/hip_runtime.h>
#include <stdint.h>

#define AS1 __attribute__((address_space(1)))
#define AS3 __attribute__((address_space(3)))

typedef __attribute__((ext_vector_type(4))) int i32x4;
typedef __attribute__((ext_vector_type(16))) int i32x16;

// ---------------- blend: blended[g] = sum_p routing[p] * ps[p*G+g] ----------
__global__ void blend_k(const float* __restrict__ ps, const float* __restrict__ rt,
                        float* __restrict__ blended, int G, int P) {
  int g = blockIdx.x * blockDim.x + threadIdx.x;
  if (g >= G) return;
  float s = 0.f;
  for (int p = 0; p < P; ++p) s += rt[p] * ps[(size_t)p * G + g];
  blended[g] = s;
}

__device__ __forceinline__ int q8(float v, float s) {
  int q = (int)rintf(v * s);
  q = q > 127 ? 127 : q;
  q = q < -127 ? -127 : q;
  return q & 0xff;
}

// ---------------- quantize W: w_q[i] = sign(signs[i]) * round(127*blended[i/128])
__global__ void quant_w_k(const float4* __restrict__ signs, const float* __restrict__ blended,
                          int4* __restrict__ wq, int n16) {
  int t = blockIdx.x * blockDim.x + threadIdx.x;
  if (t >= n16) return;
  float bl = blended[t >> 3];             // (t*16) >> 7
  int q = (int)rintf(bl * 127.f);
  q = q > 127 ? 127 : q; q = q < 1 ? 1 : q;
  int b[16];
#pragma unroll
  for (int i = 0; i < 4; ++i) {
    float4 s = signs[t * 4 + i];
    b[i * 4 + 0] = (s.x >= 0.f ? q : -q) & 0xff;
    b[i * 4 + 1] = (s.y >= 0.f ? q : -q) & 0xff;
    b[i * 4 + 2] = (s.z >= 0.f ? q : -q) & 0xff;
    b[i * 4 + 3] = (s.w >= 0.f ? q : -q) & 0xff;
  }
  int4 o;
  o.x = b[0] | (b[1] << 8) | (b[2] << 16) | (b[3] << 24);
  o.y = b[4] | (b[5] << 8) | (b[6] << 16) | (b[7] << 24);
  o.z = b[8] | (b[9] << 8) | (b[10] << 16) | (b[11] << 24);
  o.w = b[12] | (b[13] << 8) | (b[14] << 16) | (b[15] << 24);
  wq[t] = o;
}

// ---------------- quantize X per row: one block per row (K=4096, 256 thr) ----
__global__ __launch_bounds__(256) void quant_x_k(const float4* __restrict__ x,
                                                 int* __restrict__ xq,
                                                 float* __restrict__ rowinv, int K) {
  const int m = blockIdx.x;
  const int t = threadIdx.x;
  const int lane = t & 63;
  const int wave = t >> 6;
  const float4* xr = x + (size_t)m * (K / 4);
  float4 v[4];
  float amax = 0.f;
#pragma unroll
  for (int i = 0; i < 4; ++i) {
    v[i] = xr[t + 256 * i];
    amax = fmaxf(amax, fmaxf(fmaxf(fabsf(v[i].x), fabsf(v[i].y)),
                             fmaxf(fabsf(v[i].z), fabsf(v[i].w))));
  }
#pragma unroll
  for (int off = 1; off < 64; off <<= 1)
    amax = fmaxf(amax, __shfl_xor(amax, off));
  __shared__ float red[4];
  if (lane == 0) red[wave] = amax;
  __syncthreads();
  amax = fmaxf(fmaxf(red[0], red[1]), fmaxf(red[2], red[3]));
  const float s = 127.f / amax;
  if (t == 0) rowinv[m] = amax / (127.f * 127.f);
  int* xo = xq + (size_t)m * (K / 4);
#pragma unroll
  for (int i = 0; i < 4; ++i) {
    int p = q8(v[i].x, s) | (q8(v[i].y, s) << 8) | (q8(v[i].z, s) << 16) | (q8(v[i].w, s) << 24);
    xo[t + 256 * i] = p;
  }
}

// ---------------- i8 GEMM: C[M,N] = (A[M,K] * B[N,K]^T) * rowinv[m] ---------
// 256x256 tile, 8 waves (2Mx4N), per-wave 128x64 via 4x2 of mfma_i32_32x32x32_i8.
// K in 64-byte halves through a 4-deep LDS ring (4 x 32KiB). T3 phase split:
// each K-64 = 2 phases of {6 ds_read_b128 (this phase's frags); [stage h+3];
// s_barrier; lgkmcnt(0); setprio(1); 8 MFMA; setprio(0); s_barrier}. Reads of
// phase p+1 issue right after MFMA cluster p (pipe still draining) -> LDS
// latency hides under the drain; per-phase LDS (~48 reads/CU ~450cy) balances
// MFMA (~585cy/SIMD), m201-style. Counted vmcnt once per K-64, never 0 mid-loop.
// LDS swizzle: slot = chunk ^ ((row>>1)&3), applied source-side for the linear
// global_load_lds dest and on the ds_read addr (rule 21).
#define BM 256
#define BN 256

__global__ __launch_bounds__(512, 2) void gemm_i8_k(
    const signed char* __restrict__ A, const signed char* __restrict__ B,
    const float* __restrict__ rowinv, float* __restrict__ C, int M, int N, int K) {
  __shared__ __align__(16) signed char lds[4][2][256 * 64];   // [buf][A/B][row*64+slot*16]
  const int tid  = threadIdx.x;
  const int lane = tid & 63;
  const int wave = tid >> 6;

  // bijective XCD swizzle (nwg = 512, divisible by 8)
  int bid = blockIdx.y * gridDim.x + blockIdx.x;
  const int nwg = gridDim.x * gridDim.y;
  const int cpx = nwg >> 3;
  bid = (bid & 7) * cpx + (bid >> 3);
  const int nbx = N / BN;
  const int bn = (bid % nbx) * BN;
  const int bm = (bid / nbx) * BM;

  const int wm = (wave >> 2) * 128;
  const int wn = (wave & 3) * 64;
  const int fl = lane & 31;
  const int fh = lane >> 5;
  const int sx = (fl >> 1) & 3;   // read-side swizzle: slot = chunk ^ sx

  // loop-invariant LDS read offsets
  int offA[4], offB[2];
#pragma unroll
  for (int mi = 0; mi < 4; ++mi) offA[mi] = (wm + mi * 32 + fl) * 64;
#pragma unroll
  for (int ni = 0; ni < 2; ++ni) offB[ni] = (wn + ni * 32 + fl) * 64;
  const int c0 = ((0 + fh) ^ sx) * 16;   // ks=0 chunk
  const int c1 = ((2 + fh) ^ sx) * 16;   // ks=1 chunk

  i32x16 acc[4][2];
#pragma unroll
  for (int i = 0; i < 4; ++i)
#pragma unroll
    for (int j = 0; j < 2; ++j)
#pragma unroll
      for (int r = 0; r < 16; ++r) acc[i][j][r] = 0;

  // Staging: one global_load_lds = 64 lanes x 16B = 16 rows of 64B (linear
  // dest, lane l -> row R0+(l>>2), slot l&3). Source chunk pre-swizzled:
  // c = (l&3) ^ ((l>>3)&3) so slot s of row r holds chunk s ^ ((r>>1)&3).
  const int sl   = (lane & 3) ^ ((lane >> 3) & 3);
  const int srow = lane >> 2;
  const int rA0 = 16 * (2 * wave + 0) + srow;
  const int rA1 = 16 * (2 * wave + 1) + srow;
  const signed char* gA0 = A + (size_t)(bm + rA0) * K + sl * 16;
  const signed char* gA1 = A + (size_t)(bm + rA1) * K + sl * 16;
  const signed char* gB0 = B + (size_t)(bn + rA0) * K + sl * 16;
  const signed char* gB1 = B + (size_t)(bn + rA1) * K + sl * 16;

#define STAGE(hh)                                                                \
  {                                                                              \
    const int q_  = (hh) & 3;                                                    \
    const int ko_ = (hh) * 64;                                                   \
    __builtin_amdgcn_global_load_lds((AS1 unsigned int*)(gA0 + ko_),             \
        (AS3 unsigned int*)(&lds[q_][0][(2 * wave + 0) * 1024]), 16, 0, 0);      \
    __builtin_amdgcn_global_load_lds((AS1 unsigned int*)(gA1 + ko_),             \
        (AS3 unsigned int*)(&lds[q_][0][(2 * wave + 1) * 1024]), 16, 0, 0);      \
    __builtin_amdgcn_global_load_lds((AS1 unsigned int*)(gB0 + ko_),             \
        (AS3 unsigned int*)(&lds[q_][1][(2 * wave + 0) * 1024]), 16, 0, 0);      \
    __builtin_amdgcn_global_load_lds((AS1 unsigned int*)(gB1 + ko_),             \
        (AS3 unsigned int*)(&lds[q_][1][(2 * wave + 1) * 1024]), 16, 0, 0);      \
  }

  const int NH = K >> 6;   // 64-byte halves of K
  STAGE(0); STAGE(1); STAGE(2);
  asm volatile("s_waitcnt vmcnt(8)" ::: "memory");   // half 0 resident
  __builtin_amdgcn_s_barrier();

  for (int h = 0; h < NH; ++h) {
    const signed char* Ab = &lds[h & 3][0][0];
    const signed char* Bb = &lds[h & 3][1][0];

    // ---- phase A: reads (ks=0) + stage, then barrier/lgkm/MFMA/barrier ----
    i32x4 af0[4], bf0[2];
#pragma unroll
    for (int mi = 0; mi < 4; ++mi) af0[mi] = *(const i32x4*)(Ab + offA[mi] + c0);
#pragma unroll
    for (int ni = 0; ni < 2; ++ni) bf0[ni] = *(const i32x4*)(Bb + offB[ni] + c0);
    if (h + 3 < NH) STAGE(h + 3);   // overwrites buf (h-1)&3: consumed last iter
    __builtin_amdgcn_s_barrier();
    asm volatile("s_waitcnt lgkmcnt(0)" ::: "memory");
    __builtin_amdgcn_s_setprio(1);
#pragma unroll
    for (int mi = 0; mi < 4; ++mi)
#pragma unroll
      for (int ni = 0; ni < 2; ++ni)
        acc[mi][ni] = __builtin_amdgcn_mfma_i32_32x32x32_i8(
            af0[mi], bf0[ni], acc[mi][ni], 0, 0, 0);
    __builtin_amdgcn_s_setprio(0);
    __builtin_amdgcn_s_barrier();

    // ---- phase B: reads (ks=1), then barrier/lgkm/MFMA/vmcnt/barrier ----
    i32x4 af1[4], bf1[2];
#pragma unroll
    for (int mi = 0; mi < 4; ++mi) af1[mi] = *(const i32x4*)(Ab + offA[mi] + c1);
#pragma unroll
    for (int ni = 0; ni < 2; ++ni) bf1[ni] = *(const i32x4*)(Bb + offB[ni] + c1);
    __builtin_amdgcn_s_barrier();
    asm volatile("s_waitcnt lgkmcnt(0)" ::: "memory");
    __builtin_amdgcn_s_setprio(1);
#pragma unroll
    for (int mi = 0; mi < 4; ++mi)
#pragma unroll
      for (int ni = 0; ni < 2; ++ni)
        acc[mi][ni] = __builtin_amdgcn_mfma_i32_32x32x32_i8(
            af1[mi], bf1[ni], acc[mi][ni], 0, 0, 0);
    __builtin_amdgcn_s_setprio(0);

    // retire through half h+1 (needed next iter); keep the rest in flight
    if (h + 3 < NH)      asm volatile("s_waitcnt vmcnt(8)" ::: "memory");
    else if (h + 2 < NH) asm volatile("s_waitcnt vmcnt(4)" ::: "memory");
    else if (h + 1 < NH) asm volatile("s_waitcnt vmcnt(0)" ::: "memory");
    __builtin_amdgcn_s_barrier();
  }
#undef STAGE

  // C/D layout (32x32): col = lane&31, row = (reg&3) + 8*(reg>>2) + 4*(lane>>5)
#pragma unroll
  for (int mi = 0; mi < 4; ++mi) {
    const int rbase = bm + wm + mi * 32 + 4 * fh;
    float ri[16];
#pragma unroll
    for (int r = 0; r < 16; ++r) ri[r] = rowinv[rbase + (r & 3) + 8 * (r >> 2)];
#pragma unroll
    for (int ni = 0; ni < 2; ++ni) {
      const int col = bn + wn + ni * 32 + fl;
#pragma unroll
      for (int r = 0; r < 16; ++r) {
        const int row = rbase + (r & 3) + 8 * (r >> 2);
        C[(size_t)row * N + col] = (float)acc[mi][ni][r] * ri[r];
      }
    }
  }
}

// Safety-net exact fp32 kernel (only if ws_size too small) — slow but correct.
__global__ void naive_k(const float* __restrict__ x, const float* __restrict__ signs,
                        const float* __restrict__ ps, const float* __restrict__ rt,
                        float* __restrict__ out, int M, int N, int K, int P) {
  int idx = blockIdx.x * blockDim.x + threadIdx.x;
  if (idx >= M * N) return;
  int m = idx / N, n = idx % N;
  const float* xr = x + (size_t)m * K;
  const float* wr = signs + (size_t)n * K;
  const int NG = K / 128;
  const size_t G = (size_t)N * NG;
  float acc = 0.f;
  for (int g = 0; g < NG; ++g) {
    float sc = 0.f;
    int gi = n * NG + g;
    for (int p = 0; p < P; ++p) sc += rt[p] * ps[(size_t)p * G + gi];
    float s2 = 0.f;
    for (int kk = 0; kk < 128; ++kk) s2 += xr[g * 128 + kk] * wr[g * 128 + kk];
    acc += sc * s2;
  }
  out[idx] = acc;
}

extern "C" void kernel_launch(void* const* d_in, const int* in_sizes, int n_in,
                              void* d_out, int out_size, void* d_ws, size_t ws_size,
                              hipStream_t stream) {
  const float* x     = (const float*)d_in[0];
  const float* signs = (const float*)d_in[1];
  const float* ps    = (const float*)d_in[2];
  const float* rt    = (const float*)d_in[3];
  float* out = (float*)d_out;

  const int K = 4096, N = 4096, GS = 128;
  const int M = in_sizes[0] / K;   // 8192
  const int G = N / GS * K;        // 131072 flat groups over [N*K]
  const int P = in_sizes[3];       // 8

  const size_t xq_bytes = (size_t)M * K;       // 33.5 MB
  const size_t wq_bytes = (size_t)N * K;       // 16.8 MB
  const size_t bl_bytes = (size_t)G * 4;       // 0.5 MB
  const size_t ri_bytes = (size_t)M * 4;       // 32 KB
  const size_t need = xq_bytes + wq_bytes + bl_bytes + ri_bytes;

  if (ws_size >= need && (M % BM) == 0) {
    signed char* xq = (signed char*)d_ws;
    signed char* wq = (signed char*)((char*)d_ws + xq_bytes);
    float* blended  = (float*)((char*)d_ws + xq_bytes + wq_bytes);
    float* rowinv   = (float*)((char*)d_ws + xq_bytes + wq_bytes + bl_bytes);

    blend_k<<<(G + 255) / 256, 256, 0, stream>>>(ps, rt, blended, G, P);

    const int n16w = N * K / 16;
    quant_w_k<<<(n16w + 255) / 256, 256, 0, stream>>>(
        (const float4*)signs, blended, (int4*)wq, n16w);

    quant_x_k<<<M, 256, 0, stream>>>((const float4*)x, (int*)xq, rowinv, K);

    dim3 grid(N / BN, M / BM);
    gemm_i8_k<<<grid, 512, 0, stream>>>(xq, wq, rowinv, out, M, N, K);
  } else {
    const size_t total = (size_t)M * N;
    naive_k<<<(int)((total + 255) / 256), 256, 0, stream>>>(
        x, signs, ps, rt, out, M, N, K, P);
  }
}